// Round 18
// baseline (184.913 us; speedup 1.0000x reference)
//
#include <hip/hip_runtime.h>
#include <hip/hip_bf16.h>
#include <hip/hip_fp16.h>

// B=2, Cin=512, C=64, H=W=48, N=2304 spatial, 4608 total columns.
// R18 = exact R17 pipeline (177.7us best) + ONE change:
//   upsample heads 1-3 use double-depth bands (6 nt stores/thread between
//   barriers vs 3) to test the store-issue/barrier-amortization hypothesis
//   for the residual ~40us over the 63us write floor. Head3 = 70% of bytes.
// Upsample history: 138 -> 125 (nt) -> 112 (6-load) -> ~103 (LDS band).

typedef __attribute__((ext_vector_type(8))) short short8;
typedef __attribute__((ext_vector_type(4))) float f32x4;

#define GLOAD_LDS(gsrc, ldst) \
  __builtin_amdgcn_global_load_lds((const __attribute__((address_space(1))) void*)(gsrc), \
                                   (__attribute__((address_space(3))) void*)(ldst), 16, 0, 0)

// ---------------- ws layout (float offsets) ----------------
static constexpr size_t OFF_P1 = 0;                       // [2][512]
static constexpr size_t OFF_P3 = OFF_P1 + 2*512;          // [2*9][512]
static constexpr size_t OFF_P5 = OFF_P3 + 18*512;         // [2*25][512]
static constexpr size_t OFF_G0 = OFF_P5 + 50*512;         // [2*1][64]
static constexpr size_t OFF_G1 = OFF_G0 + 2*64;           // [2*9][64]
static constexpr size_t OFF_G2 = OFF_G1 + 18*64;          // [2*25][64]
static constexpr size_t OFF_S  = OFF_G2 + 50*64;          // [2][64][2304] f32
static constexpr size_t OFF_Q  = OFF_S  + 294912;         // [2][8][2304] f32
static constexpr size_t OFF_K  = OFF_Q  + 36864;          // [2][8][2304] f32
static constexpr size_t OFF_V  = OFF_K  + 36864;          // bf16 [2][64][2304]
static constexpr size_t OFF_SA = OFF_V  + 294912;         // [2][64][2304] f32
static constexpr size_t OFF_GC = OFF_SA + 294912;         // [3][2][64][2304] f32
static constexpr size_t OFF_MEAN = OFF_GC + 3*294912;     // [2][64]
static constexpr size_t OFF_WGT  = OFF_MEAN + 512;        // (unused)
static constexpr size_t OFF_Y0 = OFF_WGT + 512;           // [2][256][2304]
static constexpr size_t OFF_Y1 = OFF_Y0 + 1179648;        // [2][128][2304]
static constexpr size_t OFF_Y2 = OFF_Y1 + 589824;         // [2][64][2304]
static constexpr size_t OFF_Y3 = OFF_Y2 + 294912;         // [2][64][2304]

// ================= LAUNCH A: sgemm_qkv (0..143) + pool (144..1167) =================
struct SgemmSmem {
  float wt[64][66];
  float xs[64][32];
  float s_lds[64][36];
  float wq_lds[80][64];
  float bqkv[80];
};
struct PoolSmem { float pl[2304]; float red[4]; };

__device__ void sgemm_qkv_body(char* smem, int cb, const float* __restrict__ x,
    const float* __restrict__ w, const float* __restrict__ bias,
    const float* __restrict__ wq, const float* __restrict__ bq,
    const float* __restrict__ wk, const float* __restrict__ bk,
    const float* __restrict__ wv, const float* __restrict__ bv,
    float* __restrict__ wsp){
  SgemmSmem& s = *reinterpret_cast<SgemmSmem*>(smem);
  int b = cb / 72, hw0 = (cb - b*72)*32;
  int tid = threadIdx.x;
  int wv_ = tid >> 6, lane = tid & 63;
  for (int i = tid; i < 5120; i += 256){
    int row = i >> 6, k = i & 63;
    s.wq_lds[row][k] = (row < 8) ? wq[(size_t)row*64 + k]
                     : (row < 16) ? wk[(size_t)(row-8)*64 + k]
                                  : wv[(size_t)(row-16)*64 + k];
  }
  if (tid < 80) s.bqkv[tid] = (tid < 8) ? bq[tid] : (tid < 16) ? bk[tid-8] : bv[tid-16];
  int sr = tid >> 2, sseg = tid & 3;
  int cc0 = (tid & 7)*4, r0 = (tid >> 3)*2;
  const float* xb = x + (size_t)b*512*2304 + hw0;
  float acc[2][4] = {};
  for (int kc = 0; kc < 512; kc += 64){
    __syncthreads();
    {
      int rr0 = wv_*16 + (lane >> 3);
      const float* g0 = xb + (size_t)(kc + rr0)*2304 + (lane & 7)*4;
      const float* g1 = xb + (size_t)(kc + rr0 + 8)*2304 + (lane & 7)*4;
      GLOAD_LDS(g0, &s.xs[wv_*16][0]);
      GLOAD_LDS(g1, &s.xs[wv_*16 + 8][0]);
    }
    #pragma unroll
    for (int i = 0; i < 16; i += 4){
      float4 v = *(const float4*)(w + (size_t)sr*512 + kc + sseg*16 + i);
      s.wt[sseg*16+i+0][sr]=v.x; s.wt[sseg*16+i+1][sr]=v.y;
      s.wt[sseg*16+i+2][sr]=v.z; s.wt[sseg*16+i+3][sr]=v.w;
    }
    __syncthreads();
    #pragma unroll 4
    for (int k = 0; k < 64; k++){
      float2 wv2 = *(const float2*)&s.wt[k][r0];
      float4 xv = *(const float4*)&s.xs[k][cc0];
      acc[0][0]+=wv2.x*xv.x; acc[0][1]+=wv2.x*xv.y; acc[0][2]+=wv2.x*xv.z; acc[0][3]+=wv2.x*xv.w;
      acc[1][0]+=wv2.y*xv.x; acc[1][1]+=wv2.y*xv.y; acc[1][2]+=wv2.y*xv.z; acc[1][3]+=wv2.y*xv.w;
    }
  }
  #pragma unroll
  for (int i = 0; i < 2; i++){
    float bi = bias[r0+i];
    float4 o;
    o.x = fmaxf(acc[i][0]+bi, 0.f); o.y = fmaxf(acc[i][1]+bi, 0.f);
    o.z = fmaxf(acc[i][2]+bi, 0.f); o.w = fmaxf(acc[i][3]+bi, 0.f);
    *(float4*)(wsp + OFF_S + ((size_t)b*64 + r0+i)*2304 + hw0 + cc0) = o;
    *(float4*)&s.s_lds[r0+i][cc0] = o;
  }
  __syncthreads();
  int col = tid & 31, rgrp = tid >> 5;
  float a2[10];
  #pragma unroll
  for (int i = 0; i < 10; i++) a2[i] = s.bqkv[rgrp*10 + i];
  for (int k = 0; k < 64; k++){
    float sv = s.s_lds[k][col];
    #pragma unroll
    for (int i = 0; i < 10; i++) a2[i] += s.wq_lds[rgrp*10 + i][k]*sv;
  }
  __hip_bfloat16* Vb = reinterpret_cast<__hip_bfloat16*>(wsp + OFF_V);
  int hw = hw0 + col;
  #pragma unroll
  for (int i = 0; i < 10; i++){
    int r = rgrp*10 + i;
    if (r < 8)       wsp[OFF_Q + (size_t)b*18432 + (size_t)r*2304 + hw] = a2[i];
    else if (r < 16) wsp[OFF_K + (size_t)b*18432 + (size_t)(r-8)*2304 + hw] = a2[i];
    else             Vb[(size_t)b*147456 + (size_t)(r-16)*2304 + hw] = __float2bfloat16(a2[i]);
  }
}

__device__ void pool_body(char* smem, int bc, const float* __restrict__ x, float* __restrict__ wsp){
  PoolSmem& s = *reinterpret_cast<PoolSmem*>(smem);
  int b = bc >> 9, cin = bc & 511;
  const float* src = x + (size_t)bc * 2304;
  int t = threadIdx.x;
  float ls = 0.f;
  #pragma unroll
  for (int j = 0; j < 9; j++){ int i = t + j*256; float v = src[i]; s.pl[i] = v; ls += v; }
  #pragma unroll
  for (int o = 32; o; o >>= 1) ls += __shfl_xor(ls, o);
  if ((t & 63) == 0) s.red[t >> 6] = ls;
  __syncthreads();
  if (t == 0) wsp[OFF_P1 + (size_t)b*512 + cin] = (s.red[0]+s.red[1]+s.red[2]+s.red[3]) * (1.f/2304.f);
  if (t < 9){
    int ry = t/3, rx = t%3; float sm = 0.f;
    for (int yy = 0; yy < 16; yy++)
      for (int xx = 0; xx < 16; xx++) sm += s.pl[(ry*16+yy)*48 + rx*16+xx];
    wsp[OFF_P3 + ((size_t)b*9 + t)*512 + cin] = sm * (1.f/256.f);
  } else if (t < 34){
    int j = t - 9; int ry = j/5, rx = j%5;
    int hs = (ry*48)/5, he = ((ry+1)*48+4)/5, cs = (rx*48)/5, ce = ((rx+1)*48+4)/5;
    float sm = 0.f;
    for (int yy = hs; yy < he; yy++)
      for (int xx = cs; xx < ce; xx++) sm += s.pl[yy*48+xx];
    wsp[OFF_P5 + ((size_t)b*25 + j)*512 + cin] = sm / (float)((he-hs)*(ce-cs));
  }
}

__global__ __launch_bounds__(256) void k_sgemm_pool(const float* __restrict__ x,
    const float* __restrict__ w, const float* __restrict__ bias,
    const float* __restrict__ wq, const float* __restrict__ bq,
    const float* __restrict__ wk, const float* __restrict__ bk,
    const float* __restrict__ wv, const float* __restrict__ bv,
    float* __restrict__ wsp){
  __shared__ __align__(16) char smem[sizeof(SgemmSmem)];
  int bx = blockIdx.x;
  if (bx < 144) sgemm_qkv_body(smem, bx, x, w, bias, wq, bq, wk, bk, wv, bv, wsp);
  else          pool_body(smem, bx - 144, x, wsp);
}

// ---------------- LAUNCH C: attn (0..287) + gcconv (288..357) ----------------
__device__ void attn_body(int blk, float* __restrict__ wsp, const float* __restrict__ gamma,
                          float (*qs)[8], unsigned short (*plds)[2312],
                          float (*redM)[16], float (*redS)[16], float (*tile)[68]){
  int mb = (blk % 144) * 16;
  int b  = blk / 144;
  int t = threadIdx.x;
  int w = t >> 6, lane = t & 63;
  int arow = lane & 15, kg = lane >> 4;
  const float* Qp = wsp + OFF_Q + (size_t)b*18432;
  const float* Kp = wsp + OFF_K + (size_t)b*18432;
  if (t < 128) qs[t>>3][t&7] = Qp[(size_t)(t&7)*2304 + mb + (t>>3)];
  __syncthreads();
  float k8[9][8];
  #pragma unroll
  for (int j = 0; j < 9; j++){
    int n = j*256 + t;
    #pragma unroll
    for (int c = 0; c < 8; c++) k8[j][c] = Kp[(size_t)c*2304 + n];
  }
  float mx[16], ssum[16];
  #pragma unroll
  for (int m = 0; m < 16; m++){
    float q0=qs[m][0], q1=qs[m][1], q2=qs[m][2], q3=qs[m][3];
    float q4=qs[m][4], q5=qs[m][5], q6=qs[m][6], q7=qs[m][7];
    float lmx = -1e30f, ls = 0.f;
    #pragma unroll
    for (int j = 0; j < 9; j++){
      float l = q0*k8[j][0]+q1*k8[j][1]+q2*k8[j][2]+q3*k8[j][3]
              + q4*k8[j][4]+q5*k8[j][5]+q6*k8[j][6]+q7*k8[j][7];
      __half hv = __float2half(l);
      plds[m][j*256 + t] = __half_as_ushort(hv);
      float mo = lmx;
      lmx = fmaxf(lmx, l);
      ls = ls*__expf(mo - lmx) + __expf(l - lmx);
    }
    mx[m] = lmx; ssum[m] = ls;
  }
  #pragma unroll
  for (int m = 0; m < 16; m++){
    float M = mx[m], S = ssum[m];
    #pragma unroll
    for (int off = 32; off; off >>= 1){
      float oM = __shfl_xor(M, off), oS = __shfl_xor(S, off);
      float nM = fmaxf(M, oM);
      S = S*__expf(M - nM) + oS*__expf(oM - nM);
      M = nM;
    }
    if (lane == 0){ redM[w][m] = M; redS[w][m] = S; }
  }
  __syncthreads();
  float Mf[16], invS[16];
  #pragma unroll
  for (int m = 0; m < 16; m++){
    float M0 = redM[0][m], M1 = redM[1][m], M2 = redM[2][m], M3 = redM[3][m];
    float M = fmaxf(fmaxf(M0, M1), fmaxf(M2, M3));
    float S = redS[0][m]*__expf(M0-M) + redS[1][m]*__expf(M1-M)
            + redS[2][m]*__expf(M2-M) + redS[3][m]*__expf(M3-M);
    Mf[m] = M; invS[m] = 1.f/S;
  }
  const short* Vb = (const short*)(wsp + OFF_V) + (size_t)b*147456 + (size_t)(w*16 + arow)*2304;
  f32x4 acc = {0.f, 0.f, 0.f, 0.f};
  for (int j = 0; j < 9; j++){
    int n = j*256 + t;
    #pragma unroll
    for (int m = 0; m < 16; m++){
      float l = __half2float(__ushort_as_half(plds[m][n]));
      float p = __expf(l - Mf[m]) * invS[m];
      __hip_bfloat16 pb = __float2bfloat16(p);
      plds[m][n] = *(unsigned short*)&pb;
    }
    __syncthreads();
    #pragma unroll
    for (int ks = 0; ks < 8; ks++){
      int nb = j*256 + ks*32 + kg*8;
      short8 a  = *(const short8*)&plds[arow][nb];
      short8 bv = *(const short8*)(Vb + nb);
      acc = __builtin_amdgcn_mfma_f32_16x16x32_bf16(a, bv, acc, 0, 0, 0);
    }
  }
  #pragma unroll
  for (int r = 0; r < 4; r++) tile[kg*4 + r][w*16 + arow] = acc[r];
  __syncthreads();
  int c = t >> 2, mq = t & 3;
  float g = gamma[0];
  const float* Sp = wsp + OFF_S + (size_t)b*147456 + (size_t)c*2304 + mb + mq*4;
  float4 s4 = *(const float4*)Sp;
  float4 o;
  o.x = g*tile[mq*4+0][c] + s4.x;
  o.y = g*tile[mq*4+1][c] + s4.y;
  o.z = g*tile[mq*4+2][c] + s4.z;
  o.w = g*tile[mq*4+3][c] + s4.w;
  *(float4*)(wsp + OFF_SA + (size_t)b*147456 + (size_t)c*2304 + mb + mq*4) = o;
}

__device__ void gcconv_body(int col,
    const float* __restrict__ w0, const float* __restrict__ b0,
    const float* __restrict__ w1, const float* __restrict__ b1,
    const float* __restrict__ w2, const float* __restrict__ b2,
    float* __restrict__ wsp){
  const float* w; const float* bias; const float* pool; float* dst;
  if (col < 2){ w = w0; bias = b0; pool = wsp + OFF_P1 + (size_t)col*512; dst = wsp + OFF_G0 + (size_t)col*64; }
  else if (col < 20){ int c = col-2;  w = w1; bias = b1; pool = wsp + OFF_P3 + (size_t)c*512; dst = wsp + OFF_G1 + (size_t)c*64; }
  else              { int c = col-20; w = w2; bias = b2; pool = wsp + OFF_P5 + (size_t)c*512; dst = wsp + OFF_G2 + (size_t)c*64; }
  int t = threadIdx.x; int r = t >> 2, qd = t & 3;
  const float* wr = w + (size_t)r*512 + qd*128;
  const float* pr = pool + qd*128;
  float acc = 0.f;
  #pragma unroll 8
  for (int k = 0; k < 128; k += 4){
    float4 wv = *(const float4*)(wr + k); float4 pv = *(const float4*)(pr + k);
    acc += wv.x*pv.x + wv.y*pv.y + wv.z*pv.z + wv.w*pv.w;
  }
  acc += __shfl_xor(acc, 1); acc += __shfl_xor(acc, 2);
  if (qd == 0) dst[r] = fmaxf(acc + bias[r], 0.f);
}

__global__ __launch_bounds__(256) void k_attn_gc(float* __restrict__ wsp, const float* __restrict__ gamma,
    const float* __restrict__ w0, const float* __restrict__ b0,
    const float* __restrict__ w1, const float* __restrict__ b1,
    const float* __restrict__ w2, const float* __restrict__ b2){
  __shared__ float qs[16][8];
  __shared__ __align__(16) unsigned short plds[16][2312];
  __shared__ float redM[4][16], redS[4][16];
  __shared__ float tile[16][68];
  int bx = blockIdx.x;
  if (bx < 288) attn_body(bx, wsp, gamma, qs, plds, redM, redS, tile);
  else          gcconv_body(bx - 288, w0, b0, w1, b1, w2, b2, wsp);
}

// ---------------- gcup (0..3455) + gap (3456..3583) ----------------
__device__ void gcup_body(int u, float* __restrict__ wsp){
  int px = (u % 9)*256 + threadIdx.x;      // 0..2303
  int pb = u / 9;                          // t*128 + b*64 + c
  int c = pb & 63, b = (pb >> 6) & 1, t = pb >> 7;
  int oy = px / 48, ox = px - oy*48;
  int ps; const float* g;
  if (t == 0){ ps = 1; g = wsp + OFF_G0 + (size_t)b*64; }
  else if (t == 1){ ps = 3; g = wsp + OFF_G1 + (size_t)b*9*64; }
  else { ps = 5; g = wsp + OFF_G2 + (size_t)b*25*64; }
  float scale = (ps - 1) / 47.f;
  float cy = oy*scale, cx = ox*scale;
  int y0 = (int)cy, x0 = (int)cx;
  float wy = cy - y0, wx = cx - x0;
  int y1 = min(y0+1, ps-1), x1 = min(x0+1, ps-1);
  float a  = g[(y0*ps+x0)*64 + c], bq = g[(y0*ps+x1)*64 + c];
  float cc = g[(y1*ps+x0)*64 + c], d  = g[(y1*ps+x1)*64 + c];
  float v = (a*(1.f-wx) + bq*wx)*(1.f-wy) + (cc*(1.f-wx) + d*wx)*wy;
  wsp[OFF_GC + (((size_t)t*2 + b)*64 + c)*2304 + px] = v;
}

__device__ void gap_body(int blk, float* __restrict__ wsp){
  __shared__ float red[4];
  int c = blk & 63, b = blk >> 6;          // 128 blocks
  const float* src = wsp + OFF_SA + ((size_t)b*64 + c)*2304;
  float s = 0.f;
  for (int i = threadIdx.x; i < 2304; i += 256) s += src[i];
  #pragma unroll
  for (int o = 32; o; o >>= 1) s += __shfl_xor(s, o);
  if ((threadIdx.x & 63) == 0) red[threadIdx.x >> 6] = s;
  __syncthreads();
  if (threadIdx.x == 0)
    wsp[OFF_MEAN + (size_t)b*64 + c] = (red[0]+red[1]+red[2]+red[3]) * (1.f/2304.f);
}

__global__ __launch_bounds__(256) void k_gcup_gap(float* __restrict__ wsp){
  int bx = blockIdx.x;
  if (bx < 3456) gcup_body(bx, wsp);
  else           gap_body(bx - 3456, wsp);
}

// ---------------- K12: out-head GEMMs, SE computed in prologue ----------------
__global__ __launch_bounds__(256) void k_outgemm(
    const float* __restrict__ w0, const float* __restrict__ b0,
    const float* __restrict__ w1, const float* __restrict__ b1,
    const float* __restrict__ w2, const float* __restrict__ b2,
    const float* __restrict__ w3, const float* __restrict__ b3,
    const float* __restrict__ w_se1, const float* __restrict__ w_se2,
    const float* __restrict__ w_se3, const float* __restrict__ w_se4,
    float* __restrict__ wsp){
  __shared__ __align__(16) float wt[64][68];
  __shared__ __align__(16) float xsh[64][64];   // staged activation chunk (16 KB, linear)
  __shared__ float wg[256];
  __shared__ float mean_lds[4][64];
  __shared__ float sh[4][64];
  int cb = blockIdx.x, rb = blockIdx.y;
  int b = cb / 36, hw0 = (cb - b*36)*64;
  int tid = threadIdx.x;
  // ---- SE prologue: wg[256] = softmax(sigmoid(w_se . means)) for batch b ----
  {
    int g = tid >> 6, c = tid & 63;
    float mv;
    if (g == 0){
      mv = wsp[OFF_MEAN + (size_t)b*64 + c];
    } else if (g == 3){
      mv = wsp[OFF_G0 + (size_t)b*64 + c];
    } else if (g == 2){
      float w3v[3] = {0.f,0.f,0.f};
      for (int o = 0; o < 48; o++){
        float cc = o*(2.f/47.f); int i0 = (int)cc; float f = cc - i0;
        int i1 = min(i0+1, 2);
        w3v[i0] += 1.f - f; w3v[i1] += f;
      }
      float s = 0.f;
      for (int sy = 0; sy < 3; sy++)
        for (int sx = 0; sx < 3; sx++)
          s += w3v[sy]*w3v[sx]*wsp[OFF_G1 + ((size_t)b*9 + sy*3 + sx)*64 + c];
      mv = s * (1.f/(48.f*48.f));
    } else {
      float w5v[5] = {0.f,0.f,0.f,0.f,0.f};
      for (int o = 0; o < 48; o++){
        float cc = o*(4.f/47.f); int i0 = (int)cc; float f = cc - i0;
        int i1 = min(i0+1, 4);
        w5v[i0] += 1.f - f; w5v[i1] += f;
      }
      float s = 0.f;
      for (int sy = 0; sy < 5; sy++)
        for (int sx = 0; sx < 5; sx++)
          s += w5v[sy]*w5v[sx]*wsp[OFF_G2 + ((size_t)b*25 + sy*5 + sx)*64 + c];
      mv = s * (1.f/(48.f*48.f));
    }
    mean_lds[g][c] = mv;
    __syncthreads();
    const float* wse = (g == 0) ? w_se1 : (g == 1) ? w_se2 : (g == 2) ? w_se3 : w_se4;
    float acc = 0.f;
    for (int j = 0; j < 64; j++) acc += wse[(size_t)c*64 + j]*mean_lds[g][j];
    float sg = 1.f / (1.f + __expf(-acc));
    sh[g][c] = sg;
    __syncthreads();
    float a0 = sh[0][c], a1 = sh[1][c], a2 = sh[2][c], a3 = sh[3][c];
    float mxv = fmaxf(fmaxf(a0, a1), fmaxf(a2, a3));
    float e = __expf(sg - mxv);
    float sum = __expf(a0-mxv) + __expf(a1-mxv) + __expf(a2-mxv) + __expf(a3-mxv);
    wg[g*64 + c] = e / sum;
  }
  // ---- GEMM ----
  const float* wsrc; const float* bsrc; size_t dstoff; int dstC; int row0;
  if (rb < 4){ wsrc = w0 + (size_t)rb*64*256; bsrc = b0 + rb*64; dstoff = OFF_Y0; dstC = 256; row0 = rb*64; }
  else if (rb < 6){ wsrc = w1 + (size_t)(rb-4)*64*256; bsrc = b1 + (rb-4)*64; dstoff = OFF_Y1; dstC = 128; row0 = (rb-4)*64; }
  else if (rb == 6){ wsrc = w2; bsrc = b2; dstoff = OFF_Y2; dstC = 64; row0 = 0; }
  else { wsrc = w3; bsrc = b3; dstoff = OFF_Y3; dstC = 64; row0 = 0; }
  int wv_ = tid >> 6, lane = tid & 63;
  int sr = tid >> 2, sseg = tid & 3;
  int cc0 = (tid & 15)*4, r0 = (tid >> 4)*4;
  float acc[4][4] = {};
  for (int kc = 0; kc < 256; kc += 64){
    __syncthreads();
    {
      int gidx = kc >> 6;
      size_t srcbase = (gidx < 3) ? OFF_GC + ((size_t)(gidx*2 + b))*147456
                                  : OFF_SA + (size_t)b*147456;
      const float* gb = wsp + srcbase + hw0 + (lane & 15)*4;
      int rr = wv_*16 + (lane >> 4);
      #pragma unroll
      for (int i = 0; i < 4; i++)
        GLOAD_LDS(gb + (size_t)(rr + i*4)*2304, &xsh[wv_*16 + i*4][0]);
    }
    #pragma unroll
    for (int i = 0; i < 16; i += 4){
      float4 v = *(const float4*)(wsrc + (size_t)sr*256 + kc + sseg*16 + i);
      int kl = sseg*16 + i;
      wt[kl+0][sr]=v.x*wg[kc+kl+0]; wt[kl+1][sr]=v.y*wg[kc+kl+1];
      wt[kl+2][sr]=v.z*wg[kc+kl+2]; wt[kl+3][sr]=v.w*wg[kc+kl+3];
    }
    __syncthreads();
    #pragma unroll 4
    for (int k = 0; k < 64; k++){
      float4 wv = *(const float4*)&wt[k][r0];
      float4 xv = *(const float4*)&xsh[k][cc0];
      acc[0][0]+=wv.x*xv.x; acc[0][1]+=wv.x*xv.y; acc[0][2]+=wv.x*xv.z; acc[0][3]+=wv.x*xv.w;
      acc[1][0]+=wv.y*xv.x; acc[1][1]+=wv.y*xv.y; acc[1][2]+=wv.y*xv.z; acc[1][3]+=wv.y*xv.w;
      acc[2][0]+=wv.z*xv.x; acc[2][1]+=wv.z*xv.y; acc[2][2]+=wv.z*xv.z; acc[2][3]+=wv.z*xv.w;
      acc[3][0]+=wv.w*xv.x; acc[3][1]+=wv.w*xv.y; acc[3][2]+=wv.w*xv.z; acc[3][3]+=wv.w*xv.w;
    }
  }
  #pragma unroll
  for (int i = 0; i < 4; i++){
    float bi = bsrc[r0+i];
    float4 o;
    o.x = fmaxf(acc[i][0]+bi, 0.f); o.y = fmaxf(acc[i][1]+bi, 0.f);
    o.z = fmaxf(acc[i][2]+bi, 0.f); o.w = fmaxf(acc[i][3]+bi, 0.f);
    *(float4*)(wsp + dstoff + ((size_t)b*dstC + row0 + r0 + i)*2304 + hw0 + cc0) = o;
  }
}

// ---------------- K13: upsample, LDS row-band + contiguous nt stores ----------------
// Heads 1-3 use double-depth bands (PASSES=6) to keep 6 nt stores in flight
// per thread between barriers. Window proofs (y1max - y0min <= NR-1):
//   head0 SC=2  RPB=32: span 15.5+1  -> NR=18 (unchanged, PASSES=3)
//   head1 SC=4  RPB=32: span 7.75+1  -> NR=10
//   head2 SC=8  RPB=16: span 1.875+1 -> NR=4
//   head3 SC=16 RPB=8 : span 0.44+1  -> NR=3
template<int SC, int RPB, int NR, int PASSES>
__device__ __forceinline__ void up_band(int bi, const float* __restrict__ src,
                                        float* __restrict__ dst, float (*srow)[48]){
  constexpr int OW = 48*SC, OH = 48*SC, OW4 = OW/4;
  constexpr float inv = 1.0f/SC;
  constexpr int BANDS = OH/RPB;
  static_assert(PASSES*256 == RPB*OW4, "band size mismatch");
  int pc = bi / BANDS, band = bi - pc*BANDS;
  int r0b = band * RPB;
  const float* sp = src + (size_t)pc * 2304;
  int y0min = (int)fmaxf((r0b + 0.5f)*inv - 0.5f, 0.f);
  int t = threadIdx.x;
  for (int i = t; i < NR*48; i += 256){
    int r = i / 48, cc = i - r*48;
    srow[r][cc] = sp[min(y0min + r, 47)*48 + cc];
  }
  __syncthreads();
  float* dbase = dst + (size_t)pc*OH*OW + (size_t)r0b*OW;
  #pragma unroll
  for (int p = 0; p < PASSES; p++){
    int local = p*256 + t;                 // f4 index within band (row-major)
    int lrow = local / OW4;
    int q = local - lrow*OW4;
    int oy = r0b + lrow;
    float cy = fminf(fmaxf((oy + 0.5f)*inv - 0.5f, 0.f), 47.f);
    int y0 = (int)cy; float wy = cy - y0;
    int y1 = min(y0 + 1, 47);
    const float* s0 = srow[min(y0 - y0min, NR-1)];
    const float* s1 = srow[min(y1 - y0min, NR-1)];
    float ov[4];
    #pragma unroll
    for (int i = 0; i < 4; i++){
      float cx = fminf(fmaxf((q*4 + i + 0.5f)*inv - 0.5f, 0.f), 47.f);
      int x0 = (int)cx; float wx = cx - x0;
      int x1 = min(x0 + 1, 47);
      float a = s0[x0] + (s0[x1] - s0[x0])*wx;
      float b = s1[x0] + (s1[x1] - s1[x0])*wx;
      ov[i] = a + (b - a)*wy;
    }
    f32x4 o; o[0]=ov[0]; o[1]=ov[1]; o[2]=ov[2]; o[3]=ov[3];
    __builtin_nontemporal_store(o, (f32x4*)(dbase + (size_t)local*4));
  }
}

__global__ __launch_bounds__(256) void k_upsample_all(const float* __restrict__ wsp, float* __restrict__ out){
  __shared__ float srow[18][48];
  int b = blockIdx.x;
  // head0: 512 planes x 3 bands  = 1536
  // head1: 256 planes x 6 bands  = 1536  (-> 3072)
  // head2: 128 planes x 24 bands = 3072  (-> 6144)
  // head3: 128 planes x 96 bands = 12288 (-> 18432)
  if (b < 1536)        up_band<2,32,18,3>(b,         wsp + OFF_Y0, out,            srow);
  else if (b < 3072)   up_band<4,32,10,6>(b - 1536,  wsp + OFF_Y1, out + 4718592,  srow);
  else if (b < 6144)   up_band<8,16,4,6> (b - 3072,  wsp + OFF_Y2, out + 14155776, srow);
  else                 up_band<16,8,3,6> (b - 6144,  wsp + OFF_Y3, out + 33030144, srow);
}

// ---------------- launcher ----------------
extern "C" void kernel_launch(void* const* d_in, const int* in_sizes, int n_in,
                              void* d_out, int out_size, void* d_ws, size_t ws_size,
                              hipStream_t stream){
  const float* x     = (const float*)d_in[0];
  const float* w_gc0 = (const float*)d_in[1];
  const float* b_gc0 = (const float*)d_in[2];
  const float* w_gc1 = (const float*)d_in[3];
  const float* b_gc1 = (const float*)d_in[4];
  const float* w_gc2 = (const float*)d_in[5];
  const float* b_gc2 = (const float*)d_in[6];
  const float* w_gc3 = (const float*)d_in[7];
  const float* b_gc3 = (const float*)d_in[8];
  const float* w_q   = (const float*)d_in[9];
  const float* b_q   = (const float*)d_in[10];
  const float* w_k   = (const float*)d_in[11];
  const float* b_k   = (const float*)d_in[12];
  const float* w_v   = (const float*)d_in[13];
  const float* b_v   = (const float*)d_in[14];
  const float* gamma = (const float*)d_in[15];
  const float* w_se1 = (const float*)d_in[16];
  const float* w_se2 = (const float*)d_in[17];
  const float* w_se3 = (const float*)d_in[18];
  const float* w_se4 = (const float*)d_in[19];
  const float* w_out0 = (const float*)d_in[20];
  const float* b_out0 = (const float*)d_in[21];
  const float* w_out1 = (const float*)d_in[22];
  const float* b_out1 = (const float*)d_in[23];
  const float* w_out2 = (const float*)d_in[24];
  const float* b_out2 = (const float*)d_in[25];
  const float* w_out3 = (const float*)d_in[26];
  const float* b_out3 = (const float*)d_in[27];
  float* wsp = (float*)d_ws;
  float* out = (float*)d_out;

  k_sgemm_pool<<<1168, 256, 0, stream>>>(x, w_gc3, b_gc3, w_q,b_q,w_k,b_k,w_v,b_v, wsp);
  k_attn_gc   <<<358,  256, 0, stream>>>(wsp, gamma, w_gc0,b_gc0,w_gc1,b_gc1,w_gc2,b_gc2);
  k_gcup_gap  <<<3584, 256, 0, stream>>>(wsp);
  k_outgemm   <<<dim3(72,8), 256, 0, stream>>>(w_out0,b_out0,w_out1,b_out1,w_out2,b_out2,w_out3,b_out3,
                                               w_se1,w_se2,w_se3,w_se4, wsp);
  k_upsample_all<<<18432, 256, 0, stream>>>(wsp, out);
}

// Round 19
// 177.536 us; speedup vs baseline: 1.0415x; 1.0415x over previous
//
#include <hip/hip_runtime.h>
#include <hip/hip_bf16.h>
#include <hip/hip_fp16.h>

// B=2, Cin=512, C=64, H=W=48, N=2304 spatial, 4608 total columns.
// R19 = exact revert to R17 (177.7us, best). R18's deeper-band upsample
// (+7.2us) falsified the store-depth hypothesis: per-wave store depth trades
// against the TLP that hides nt-store latency. Final pipeline: 5 launches,
// all merges individually validated (R12/R15/R16/R17); upsample at its
// ~4.2 TB/s practical wall (nt + LDS-band + 6-load window all banked).
// Trajectory: 308 -> 273 -> 230 -> 217 -> 215 -> 202 -> 193 -> 184 -> 177.7.

typedef __attribute__((ext_vector_type(8))) short short8;
typedef __attribute__((ext_vector_type(4))) float f32x4;

#define GLOAD_LDS(gsrc, ldst) \
  __builtin_amdgcn_global_load_lds((const __attribute__((address_space(1))) void*)(gsrc), \
                                   (__attribute__((address_space(3))) void*)(ldst), 16, 0, 0)

// ---------------- ws layout (float offsets) ----------------
static constexpr size_t OFF_P1 = 0;                       // [2][512]
static constexpr size_t OFF_P3 = OFF_P1 + 2*512;          // [2*9][512]
static constexpr size_t OFF_P5 = OFF_P3 + 18*512;         // [2*25][512]
static constexpr size_t OFF_G0 = OFF_P5 + 50*512;         // [2*1][64]
static constexpr size_t OFF_G1 = OFF_G0 + 2*64;           // [2*9][64]
static constexpr size_t OFF_G2 = OFF_G1 + 18*64;          // [2*25][64]
static constexpr size_t OFF_S  = OFF_G2 + 50*64;          // [2][64][2304] f32
static constexpr size_t OFF_Q  = OFF_S  + 294912;         // [2][8][2304] f32
static constexpr size_t OFF_K  = OFF_Q  + 36864;          // [2][8][2304] f32
static constexpr size_t OFF_V  = OFF_K  + 36864;          // bf16 [2][64][2304]
static constexpr size_t OFF_SA = OFF_V  + 294912;         // [2][64][2304] f32
static constexpr size_t OFF_GC = OFF_SA + 294912;         // [3][2][64][2304] f32
static constexpr size_t OFF_MEAN = OFF_GC + 3*294912;     // [2][64]
static constexpr size_t OFF_WGT  = OFF_MEAN + 512;        // (unused)
static constexpr size_t OFF_Y0 = OFF_WGT + 512;           // [2][256][2304]
static constexpr size_t OFF_Y1 = OFF_Y0 + 1179648;        // [2][128][2304]
static constexpr size_t OFF_Y2 = OFF_Y1 + 589824;         // [2][64][2304]
static constexpr size_t OFF_Y3 = OFF_Y2 + 294912;         // [2][64][2304]

// ================= LAUNCH A: sgemm_qkv (0..143) + pool (144..1167) =================
struct SgemmSmem {
  float wt[64][66];
  float xs[64][32];
  float s_lds[64][36];
  float wq_lds[80][64];
  float bqkv[80];
};
struct PoolSmem { float pl[2304]; float red[4]; };

__device__ void sgemm_qkv_body(char* smem, int cb, const float* __restrict__ x,
    const float* __restrict__ w, const float* __restrict__ bias,
    const float* __restrict__ wq, const float* __restrict__ bq,
    const float* __restrict__ wk, const float* __restrict__ bk,
    const float* __restrict__ wv, const float* __restrict__ bv,
    float* __restrict__ wsp){
  SgemmSmem& s = *reinterpret_cast<SgemmSmem*>(smem);
  int b = cb / 72, hw0 = (cb - b*72)*32;
  int tid = threadIdx.x;
  int wv_ = tid >> 6, lane = tid & 63;
  for (int i = tid; i < 5120; i += 256){
    int row = i >> 6, k = i & 63;
    s.wq_lds[row][k] = (row < 8) ? wq[(size_t)row*64 + k]
                     : (row < 16) ? wk[(size_t)(row-8)*64 + k]
                                  : wv[(size_t)(row-16)*64 + k];
  }
  if (tid < 80) s.bqkv[tid] = (tid < 8) ? bq[tid] : (tid < 16) ? bk[tid-8] : bv[tid-16];
  int sr = tid >> 2, sseg = tid & 3;
  int cc0 = (tid & 7)*4, r0 = (tid >> 3)*2;
  const float* xb = x + (size_t)b*512*2304 + hw0;
  float acc[2][4] = {};
  for (int kc = 0; kc < 512; kc += 64){
    __syncthreads();
    {
      int rr0 = wv_*16 + (lane >> 3);
      const float* g0 = xb + (size_t)(kc + rr0)*2304 + (lane & 7)*4;
      const float* g1 = xb + (size_t)(kc + rr0 + 8)*2304 + (lane & 7)*4;
      GLOAD_LDS(g0, &s.xs[wv_*16][0]);
      GLOAD_LDS(g1, &s.xs[wv_*16 + 8][0]);
    }
    #pragma unroll
    for (int i = 0; i < 16; i += 4){
      float4 v = *(const float4*)(w + (size_t)sr*512 + kc + sseg*16 + i);
      s.wt[sseg*16+i+0][sr]=v.x; s.wt[sseg*16+i+1][sr]=v.y;
      s.wt[sseg*16+i+2][sr]=v.z; s.wt[sseg*16+i+3][sr]=v.w;
    }
    __syncthreads();
    #pragma unroll 4
    for (int k = 0; k < 64; k++){
      float2 wv2 = *(const float2*)&s.wt[k][r0];
      float4 xv = *(const float4*)&s.xs[k][cc0];
      acc[0][0]+=wv2.x*xv.x; acc[0][1]+=wv2.x*xv.y; acc[0][2]+=wv2.x*xv.z; acc[0][3]+=wv2.x*xv.w;
      acc[1][0]+=wv2.y*xv.x; acc[1][1]+=wv2.y*xv.y; acc[1][2]+=wv2.y*xv.z; acc[1][3]+=wv2.y*xv.w;
    }
  }
  #pragma unroll
  for (int i = 0; i < 2; i++){
    float bi = bias[r0+i];
    float4 o;
    o.x = fmaxf(acc[i][0]+bi, 0.f); o.y = fmaxf(acc[i][1]+bi, 0.f);
    o.z = fmaxf(acc[i][2]+bi, 0.f); o.w = fmaxf(acc[i][3]+bi, 0.f);
    *(float4*)(wsp + OFF_S + ((size_t)b*64 + r0+i)*2304 + hw0 + cc0) = o;
    *(float4*)&s.s_lds[r0+i][cc0] = o;
  }
  __syncthreads();
  int col = tid & 31, rgrp = tid >> 5;
  float a2[10];
  #pragma unroll
  for (int i = 0; i < 10; i++) a2[i] = s.bqkv[rgrp*10 + i];
  for (int k = 0; k < 64; k++){
    float sv = s.s_lds[k][col];
    #pragma unroll
    for (int i = 0; i < 10; i++) a2[i] += s.wq_lds[rgrp*10 + i][k]*sv;
  }
  __hip_bfloat16* Vb = reinterpret_cast<__hip_bfloat16*>(wsp + OFF_V);
  int hw = hw0 + col;
  #pragma unroll
  for (int i = 0; i < 10; i++){
    int r = rgrp*10 + i;
    if (r < 8)       wsp[OFF_Q + (size_t)b*18432 + (size_t)r*2304 + hw] = a2[i];
    else if (r < 16) wsp[OFF_K + (size_t)b*18432 + (size_t)(r-8)*2304 + hw] = a2[i];
    else             Vb[(size_t)b*147456 + (size_t)(r-16)*2304 + hw] = __float2bfloat16(a2[i]);
  }
}

__device__ void pool_body(char* smem, int bc, const float* __restrict__ x, float* __restrict__ wsp){
  PoolSmem& s = *reinterpret_cast<PoolSmem*>(smem);
  int b = bc >> 9, cin = bc & 511;
  const float* src = x + (size_t)bc * 2304;
  int t = threadIdx.x;
  float ls = 0.f;
  #pragma unroll
  for (int j = 0; j < 9; j++){ int i = t + j*256; float v = src[i]; s.pl[i] = v; ls += v; }
  #pragma unroll
  for (int o = 32; o; o >>= 1) ls += __shfl_xor(ls, o);
  if ((t & 63) == 0) s.red[t >> 6] = ls;
  __syncthreads();
  if (t == 0) wsp[OFF_P1 + (size_t)b*512 + cin] = (s.red[0]+s.red[1]+s.red[2]+s.red[3]) * (1.f/2304.f);
  if (t < 9){
    int ry = t/3, rx = t%3; float sm = 0.f;
    for (int yy = 0; yy < 16; yy++)
      for (int xx = 0; xx < 16; xx++) sm += s.pl[(ry*16+yy)*48 + rx*16+xx];
    wsp[OFF_P3 + ((size_t)b*9 + t)*512 + cin] = sm * (1.f/256.f);
  } else if (t < 34){
    int j = t - 9; int ry = j/5, rx = j%5;
    int hs = (ry*48)/5, he = ((ry+1)*48+4)/5, cs = (rx*48)/5, ce = ((rx+1)*48+4)/5;
    float sm = 0.f;
    for (int yy = hs; yy < he; yy++)
      for (int xx = cs; xx < ce; xx++) sm += s.pl[yy*48+xx];
    wsp[OFF_P5 + ((size_t)b*25 + j)*512 + cin] = sm / (float)((he-hs)*(ce-cs));
  }
}

__global__ __launch_bounds__(256) void k_sgemm_pool(const float* __restrict__ x,
    const float* __restrict__ w, const float* __restrict__ bias,
    const float* __restrict__ wq, const float* __restrict__ bq,
    const float* __restrict__ wk, const float* __restrict__ bk,
    const float* __restrict__ wv, const float* __restrict__ bv,
    float* __restrict__ wsp){
  __shared__ __align__(16) char smem[sizeof(SgemmSmem)];
  int bx = blockIdx.x;
  if (bx < 144) sgemm_qkv_body(smem, bx, x, w, bias, wq, bq, wk, bk, wv, bv, wsp);
  else          pool_body(smem, bx - 144, x, wsp);
}

// ---------------- LAUNCH C: attn (0..287) + gcconv (288..357) ----------------
__device__ void attn_body(int blk, float* __restrict__ wsp, const float* __restrict__ gamma,
                          float (*qs)[8], unsigned short (*plds)[2312],
                          float (*redM)[16], float (*redS)[16], float (*tile)[68]){
  int mb = (blk % 144) * 16;
  int b  = blk / 144;
  int t = threadIdx.x;
  int w = t >> 6, lane = t & 63;
  int arow = lane & 15, kg = lane >> 4;
  const float* Qp = wsp + OFF_Q + (size_t)b*18432;
  const float* Kp = wsp + OFF_K + (size_t)b*18432;
  if (t < 128) qs[t>>3][t&7] = Qp[(size_t)(t&7)*2304 + mb + (t>>3)];
  __syncthreads();
  float k8[9][8];
  #pragma unroll
  for (int j = 0; j < 9; j++){
    int n = j*256 + t;
    #pragma unroll
    for (int c = 0; c < 8; c++) k8[j][c] = Kp[(size_t)c*2304 + n];
  }
  float mx[16], ssum[16];
  #pragma unroll
  for (int m = 0; m < 16; m++){
    float q0=qs[m][0], q1=qs[m][1], q2=qs[m][2], q3=qs[m][3];
    float q4=qs[m][4], q5=qs[m][5], q6=qs[m][6], q7=qs[m][7];
    float lmx = -1e30f, ls = 0.f;
    #pragma unroll
    for (int j = 0; j < 9; j++){
      float l = q0*k8[j][0]+q1*k8[j][1]+q2*k8[j][2]+q3*k8[j][3]
              + q4*k8[j][4]+q5*k8[j][5]+q6*k8[j][6]+q7*k8[j][7];
      __half hv = __float2half(l);
      plds[m][j*256 + t] = __half_as_ushort(hv);
      float mo = lmx;
      lmx = fmaxf(lmx, l);
      ls = ls*__expf(mo - lmx) + __expf(l - lmx);
    }
    mx[m] = lmx; ssum[m] = ls;
  }
  #pragma unroll
  for (int m = 0; m < 16; m++){
    float M = mx[m], S = ssum[m];
    #pragma unroll
    for (int off = 32; off; off >>= 1){
      float oM = __shfl_xor(M, off), oS = __shfl_xor(S, off);
      float nM = fmaxf(M, oM);
      S = S*__expf(M - nM) + oS*__expf(oM - nM);
      M = nM;
    }
    if (lane == 0){ redM[w][m] = M; redS[w][m] = S; }
  }
  __syncthreads();
  float Mf[16], invS[16];
  #pragma unroll
  for (int m = 0; m < 16; m++){
    float M0 = redM[0][m], M1 = redM[1][m], M2 = redM[2][m], M3 = redM[3][m];
    float M = fmaxf(fmaxf(M0, M1), fmaxf(M2, M3));
    float S = redS[0][m]*__expf(M0-M) + redS[1][m]*__expf(M1-M)
            + redS[2][m]*__expf(M2-M) + redS[3][m]*__expf(M3-M);
    Mf[m] = M; invS[m] = 1.f/S;
  }
  const short* Vb = (const short*)(wsp + OFF_V) + (size_t)b*147456 + (size_t)(w*16 + arow)*2304;
  f32x4 acc = {0.f, 0.f, 0.f, 0.f};
  for (int j = 0; j < 9; j++){
    int n = j*256 + t;
    #pragma unroll
    for (int m = 0; m < 16; m++){
      float l = __half2float(__ushort_as_half(plds[m][n]));
      float p = __expf(l - Mf[m]) * invS[m];
      __hip_bfloat16 pb = __float2bfloat16(p);
      plds[m][n] = *(unsigned short*)&pb;
    }
    __syncthreads();
    #pragma unroll
    for (int ks = 0; ks < 8; ks++){
      int nb = j*256 + ks*32 + kg*8;
      short8 a  = *(const short8*)&plds[arow][nb];
      short8 bv = *(const short8*)(Vb + nb);
      acc = __builtin_amdgcn_mfma_f32_16x16x32_bf16(a, bv, acc, 0, 0, 0);
    }
  }
  #pragma unroll
  for (int r = 0; r < 4; r++) tile[kg*4 + r][w*16 + arow] = acc[r];
  __syncthreads();
  int c = t >> 2, mq = t & 3;
  float g = gamma[0];
  const float* Sp = wsp + OFF_S + (size_t)b*147456 + (size_t)c*2304 + mb + mq*4;
  float4 s4 = *(const float4*)Sp;
  float4 o;
  o.x = g*tile[mq*4+0][c] + s4.x;
  o.y = g*tile[mq*4+1][c] + s4.y;
  o.z = g*tile[mq*4+2][c] + s4.z;
  o.w = g*tile[mq*4+3][c] + s4.w;
  *(float4*)(wsp + OFF_SA + (size_t)b*147456 + (size_t)c*2304 + mb + mq*4) = o;
}

__device__ void gcconv_body(int col,
    const float* __restrict__ w0, const float* __restrict__ b0,
    const float* __restrict__ w1, const float* __restrict__ b1,
    const float* __restrict__ w2, const float* __restrict__ b2,
    float* __restrict__ wsp){
  const float* w; const float* bias; const float* pool; float* dst;
  if (col < 2){ w = w0; bias = b0; pool = wsp + OFF_P1 + (size_t)col*512; dst = wsp + OFF_G0 + (size_t)col*64; }
  else if (col < 20){ int c = col-2;  w = w1; bias = b1; pool = wsp + OFF_P3 + (size_t)c*512; dst = wsp + OFF_G1 + (size_t)c*64; }
  else              { int c = col-20; w = w2; bias = b2; pool = wsp + OFF_P5 + (size_t)c*512; dst = wsp + OFF_G2 + (size_t)c*64; }
  int t = threadIdx.x; int r = t >> 2, qd = t & 3;
  const float* wr = w + (size_t)r*512 + qd*128;
  const float* pr = pool + qd*128;
  float acc = 0.f;
  #pragma unroll 8
  for (int k = 0; k < 128; k += 4){
    float4 wv = *(const float4*)(wr + k); float4 pv = *(const float4*)(pr + k);
    acc += wv.x*pv.x + wv.y*pv.y + wv.z*pv.z + wv.w*pv.w;
  }
  acc += __shfl_xor(acc, 1); acc += __shfl_xor(acc, 2);
  if (qd == 0) dst[r] = fmaxf(acc + bias[r], 0.f);
}

__global__ __launch_bounds__(256) void k_attn_gc(float* __restrict__ wsp, const float* __restrict__ gamma,
    const float* __restrict__ w0, const float* __restrict__ b0,
    const float* __restrict__ w1, const float* __restrict__ b1,
    const float* __restrict__ w2, const float* __restrict__ b2){
  __shared__ float qs[16][8];
  __shared__ __align__(16) unsigned short plds[16][2312];
  __shared__ float redM[4][16], redS[4][16];
  __shared__ float tile[16][68];
  int bx = blockIdx.x;
  if (bx < 288) attn_body(bx, wsp, gamma, qs, plds, redM, redS, tile);
  else          gcconv_body(bx - 288, w0, b0, w1, b1, w2, b2, wsp);
}

// ---------------- gcup (0..3455) + gap (3456..3583) ----------------
__device__ void gcup_body(int u, float* __restrict__ wsp){
  int px = (u % 9)*256 + threadIdx.x;      // 0..2303
  int pb = u / 9;                          // t*128 + b*64 + c
  int c = pb & 63, b = (pb >> 6) & 1, t = pb >> 7;
  int oy = px / 48, ox = px - oy*48;
  int ps; const float* g;
  if (t == 0){ ps = 1; g = wsp + OFF_G0 + (size_t)b*64; }
  else if (t == 1){ ps = 3; g = wsp + OFF_G1 + (size_t)b*9*64; }
  else { ps = 5; g = wsp + OFF_G2 + (size_t)b*25*64; }
  float scale = (ps - 1) / 47.f;
  float cy = oy*scale, cx = ox*scale;
  int y0 = (int)cy, x0 = (int)cx;
  float wy = cy - y0, wx = cx - x0;
  int y1 = min(y0+1, ps-1), x1 = min(x0+1, ps-1);
  float a  = g[(y0*ps+x0)*64 + c], bq = g[(y0*ps+x1)*64 + c];
  float cc = g[(y1*ps+x0)*64 + c], d  = g[(y1*ps+x1)*64 + c];
  float v = (a*(1.f-wx) + bq*wx)*(1.f-wy) + (cc*(1.f-wx) + d*wx)*wy;
  wsp[OFF_GC + (((size_t)t*2 + b)*64 + c)*2304 + px] = v;
}

__device__ void gap_body(int blk, float* __restrict__ wsp){
  __shared__ float red[4];
  int c = blk & 63, b = blk >> 6;          // 128 blocks
  const float* src = wsp + OFF_SA + ((size_t)b*64 + c)*2304;
  float s = 0.f;
  for (int i = threadIdx.x; i < 2304; i += 256) s += src[i];
  #pragma unroll
  for (int o = 32; o; o >>= 1) s += __shfl_xor(s, o);
  if ((threadIdx.x & 63) == 0) red[threadIdx.x >> 6] = s;
  __syncthreads();
  if (threadIdx.x == 0)
    wsp[OFF_MEAN + (size_t)b*64 + c] = (red[0]+red[1]+red[2]+red[3]) * (1.f/2304.f);
}

__global__ __launch_bounds__(256) void k_gcup_gap(float* __restrict__ wsp){
  int bx = blockIdx.x;
  if (bx < 3456) gcup_body(bx, wsp);
  else           gap_body(bx - 3456, wsp);
}

// ---------------- K12: out-head GEMMs, SE computed in prologue ----------------
__global__ __launch_bounds__(256) void k_outgemm(
    const float* __restrict__ w0, const float* __restrict__ b0,
    const float* __restrict__ w1, const float* __restrict__ b1,
    const float* __restrict__ w2, const float* __restrict__ b2,
    const float* __restrict__ w3, const float* __restrict__ b3,
    const float* __restrict__ w_se1, const float* __restrict__ w_se2,
    const float* __restrict__ w_se3, const float* __restrict__ w_se4,
    float* __restrict__ wsp){
  __shared__ __align__(16) float wt[64][68];
  __shared__ __align__(16) float xsh[64][64];   // staged activation chunk (16 KB, linear)
  __shared__ float wg[256];
  __shared__ float mean_lds[4][64];
  __shared__ float sh[4][64];
  int cb = blockIdx.x, rb = blockIdx.y;
  int b = cb / 36, hw0 = (cb - b*36)*64;
  int tid = threadIdx.x;
  // ---- SE prologue: wg[256] = softmax(sigmoid(w_se . means)) for batch b ----
  {
    int g = tid >> 6, c = tid & 63;
    float mv;
    if (g == 0){
      mv = wsp[OFF_MEAN + (size_t)b*64 + c];
    } else if (g == 3){
      mv = wsp[OFF_G0 + (size_t)b*64 + c];
    } else if (g == 2){
      float w3v[3] = {0.f,0.f,0.f};
      for (int o = 0; o < 48; o++){
        float cc = o*(2.f/47.f); int i0 = (int)cc; float f = cc - i0;
        int i1 = min(i0+1, 2);
        w3v[i0] += 1.f - f; w3v[i1] += f;
      }
      float s = 0.f;
      for (int sy = 0; sy < 3; sy++)
        for (int sx = 0; sx < 3; sx++)
          s += w3v[sy]*w3v[sx]*wsp[OFF_G1 + ((size_t)b*9 + sy*3 + sx)*64 + c];
      mv = s * (1.f/(48.f*48.f));
    } else {
      float w5v[5] = {0.f,0.f,0.f,0.f,0.f};
      for (int o = 0; o < 48; o++){
        float cc = o*(4.f/47.f); int i0 = (int)cc; float f = cc - i0;
        int i1 = min(i0+1, 4);
        w5v[i0] += 1.f - f; w5v[i1] += f;
      }
      float s = 0.f;
      for (int sy = 0; sy < 5; sy++)
        for (int sx = 0; sx < 5; sx++)
          s += w5v[sy]*w5v[sx]*wsp[OFF_G2 + ((size_t)b*25 + sy*5 + sx)*64 + c];
      mv = s * (1.f/(48.f*48.f));
    }
    mean_lds[g][c] = mv;
    __syncthreads();
    const float* wse = (g == 0) ? w_se1 : (g == 1) ? w_se2 : (g == 2) ? w_se3 : w_se4;
    float acc = 0.f;
    for (int j = 0; j < 64; j++) acc += wse[(size_t)c*64 + j]*mean_lds[g][j];
    float sg = 1.f / (1.f + __expf(-acc));
    sh[g][c] = sg;
    __syncthreads();
    float a0 = sh[0][c], a1 = sh[1][c], a2 = sh[2][c], a3 = sh[3][c];
    float mxv = fmaxf(fmaxf(a0, a1), fmaxf(a2, a3));
    float e = __expf(sg - mxv);
    float sum = __expf(a0-mxv) + __expf(a1-mxv) + __expf(a2-mxv) + __expf(a3-mxv);
    wg[g*64 + c] = e / sum;
  }
  // ---- GEMM ----
  const float* wsrc; const float* bsrc; size_t dstoff; int dstC; int row0;
  if (rb < 4){ wsrc = w0 + (size_t)rb*64*256; bsrc = b0 + rb*64; dstoff = OFF_Y0; dstC = 256; row0 = rb*64; }
  else if (rb < 6){ wsrc = w1 + (size_t)(rb-4)*64*256; bsrc = b1 + (rb-4)*64; dstoff = OFF_Y1; dstC = 128; row0 = (rb-4)*64; }
  else if (rb == 6){ wsrc = w2; bsrc = b2; dstoff = OFF_Y2; dstC = 64; row0 = 0; }
  else { wsrc = w3; bsrc = b3; dstoff = OFF_Y3; dstC = 64; row0 = 0; }
  int wv_ = tid >> 6, lane = tid & 63;
  int sr = tid >> 2, sseg = tid & 3;
  int cc0 = (tid & 15)*4, r0 = (tid >> 4)*4;
  float acc[4][4] = {};
  for (int kc = 0; kc < 256; kc += 64){
    __syncthreads();
    {
      int gidx = kc >> 6;
      size_t srcbase = (gidx < 3) ? OFF_GC + ((size_t)(gidx*2 + b))*147456
                                  : OFF_SA + (size_t)b*147456;
      const float* gb = wsp + srcbase + hw0 + (lane & 15)*4;
      int rr = wv_*16 + (lane >> 4);
      #pragma unroll
      for (int i = 0; i < 4; i++)
        GLOAD_LDS(gb + (size_t)(rr + i*4)*2304, &xsh[wv_*16 + i*4][0]);
    }
    #pragma unroll
    for (int i = 0; i < 16; i += 4){
      float4 v = *(const float4*)(wsrc + (size_t)sr*256 + kc + sseg*16 + i);
      int kl = sseg*16 + i;
      wt[kl+0][sr]=v.x*wg[kc+kl+0]; wt[kl+1][sr]=v.y*wg[kc+kl+1];
      wt[kl+2][sr]=v.z*wg[kc+kl+2]; wt[kl+3][sr]=v.w*wg[kc+kl+3];
    }
    __syncthreads();
    #pragma unroll 4
    for (int k = 0; k < 64; k++){
      float4 wv = *(const float4*)&wt[k][r0];
      float4 xv = *(const float4*)&xsh[k][cc0];
      acc[0][0]+=wv.x*xv.x; acc[0][1]+=wv.x*xv.y; acc[0][2]+=wv.x*xv.z; acc[0][3]+=wv.x*xv.w;
      acc[1][0]+=wv.y*xv.x; acc[1][1]+=wv.y*xv.y; acc[1][2]+=wv.y*xv.z; acc[1][3]+=wv.y*xv.w;
      acc[2][0]+=wv.z*xv.x; acc[2][1]+=wv.z*xv.y; acc[2][2]+=wv.z*xv.z; acc[2][3]+=wv.z*xv.w;
      acc[3][0]+=wv.w*xv.x; acc[3][1]+=wv.w*xv.y; acc[3][2]+=wv.w*xv.z; acc[3][3]+=wv.w*xv.w;
    }
  }
  #pragma unroll
  for (int i = 0; i < 4; i++){
    float bi = bsrc[r0+i];
    float4 o;
    o.x = fmaxf(acc[i][0]+bi, 0.f); o.y = fmaxf(acc[i][1]+bi, 0.f);
    o.z = fmaxf(acc[i][2]+bi, 0.f); o.w = fmaxf(acc[i][3]+bi, 0.f);
    *(float4*)(wsp + dstoff + ((size_t)b*dstC + row0 + r0 + i)*2304 + hw0 + cc0) = o;
  }
}

// ---------------- K13: upsample, LDS row-band + contiguous nt stores ----------------
template<int SC, int RPB, int NR>
__device__ __forceinline__ void up_band(int bi, const float* __restrict__ src,
                                        float* __restrict__ dst, float (*srow)[48]){
  constexpr int OW = 48*SC, OH = 48*SC, OW4 = OW/4;
  constexpr float inv = 1.0f/SC;
  constexpr int BANDS = OH/RPB;
  int pc = bi / BANDS, band = bi - pc*BANDS;
  int r0b = band * RPB;
  const float* sp = src + (size_t)pc * 2304;
  int y0min = (int)fmaxf((r0b + 0.5f)*inv - 0.5f, 0.f);
  int t = threadIdx.x;
  for (int i = t; i < NR*48; i += 256){
    int r = i / 48, cc = i - r*48;
    srow[r][cc] = sp[min(y0min + r, 47)*48 + cc];
  }
  __syncthreads();
  float* dbase = dst + (size_t)pc*OH*OW + (size_t)r0b*OW;
  #pragma unroll
  for (int p = 0; p < 3; p++){
    int local = p*256 + t;                 // f4 index within band (row-major)
    int lrow = local / OW4;
    int q = local - lrow*OW4;
    int oy = r0b + lrow;
    float cy = fminf(fmaxf((oy + 0.5f)*inv - 0.5f, 0.f), 47.f);
    int y0 = (int)cy; float wy = cy - y0;
    int y1 = min(y0 + 1, 47);
    const float* s0 = srow[min(y0 - y0min, NR-1)];
    const float* s1 = srow[min(y1 - y0min, NR-1)];
    float ov[4];
    #pragma unroll
    for (int i = 0; i < 4; i++){
      float cx = fminf(fmaxf((q*4 + i + 0.5f)*inv - 0.5f, 0.f), 47.f);
      int x0 = (int)cx; float wx = cx - x0;
      int x1 = min(x0 + 1, 47);
      float a = s0[x0] + (s0[x1] - s0[x0])*wx;
      float b = s1[x0] + (s1[x1] - s1[x0])*wx;
      ov[i] = a + (b - a)*wy;
    }
    f32x4 o; o[0]=ov[0]; o[1]=ov[1]; o[2]=ov[2]; o[3]=ov[3];
    __builtin_nontemporal_store(o, (f32x4*)(dbase + (size_t)local*4));
  }
}

__global__ __launch_bounds__(256) void k_upsample_all(const float* __restrict__ wsp, float* __restrict__ out){
  __shared__ float srow[18][48];
  int b = blockIdx.x;
  if (b < 1536)        up_band<2,32,18>(b,         wsp + OFF_Y0, out,            srow);
  else if (b < 4608)   up_band<4,16,6> (b - 1536,  wsp + OFF_Y1, out + 4718592,  srow);
  else if (b < 10752)  up_band<8,8,3>  (b - 4608,  wsp + OFF_Y2, out + 14155776, srow);
  else                 up_band<16,4,3> (b - 10752, wsp + OFF_Y3, out + 33030144, srow);
}

// ---------------- launcher ----------------
extern "C" void kernel_launch(void* const* d_in, const int* in_sizes, int n_in,
                              void* d_out, int out_size, void* d_ws, size_t ws_size,
                              hipStream_t stream){
  const float* x     = (const float*)d_in[0];
  const float* w_gc0 = (const float*)d_in[1];
  const float* b_gc0 = (const float*)d_in[2];
  const float* w_gc1 = (const float*)d_in[3];
  const float* b_gc1 = (const float*)d_in[4];
  const float* w_gc2 = (const float*)d_in[5];
  const float* b_gc2 = (const float*)d_in[6];
  const float* w_gc3 = (const float*)d_in[7];
  const float* b_gc3 = (const float*)d_in[8];
  const float* w_q   = (const float*)d_in[9];
  const float* b_q   = (const float*)d_in[10];
  const float* w_k   = (const float*)d_in[11];
  const float* b_k   = (const float*)d_in[12];
  const float* w_v   = (const float*)d_in[13];
  const float* b_v   = (const float*)d_in[14];
  const float* gamma = (const float*)d_in[15];
  const float* w_se1 = (const float*)d_in[16];
  const float* w_se2 = (const float*)d_in[17];
  const float* w_se3 = (const float*)d_in[18];
  const float* w_se4 = (const float*)d_in[19];
  const float* w_out0 = (const float*)d_in[20];
  const float* b_out0 = (const float*)d_in[21];
  const float* w_out1 = (const float*)d_in[22];
  const float* b_out1 = (const float*)d_in[23];
  const float* w_out2 = (const float*)d_in[24];
  const float* b_out2 = (const float*)d_in[25];
  const float* w_out3 = (const float*)d_in[26];
  const float* b_out3 = (const float*)d_in[27];
  float* wsp = (float*)d_ws;
  float* out = (float*)d_out;

  k_sgemm_pool<<<1168, 256, 0, stream>>>(x, w_gc3, b_gc3, w_q,b_q,w_k,b_k,w_v,b_v, wsp);
  k_attn_gc   <<<358,  256, 0, stream>>>(wsp, gamma, w_gc0,b_gc0,w_gc1,b_gc1,w_gc2,b_gc2);
  k_gcup_gap  <<<3584, 256, 0, stream>>>(wsp);
  k_outgemm   <<<dim3(72,8), 256, 0, stream>>>(w_out0,b_out0,w_out1,b_out1,w_out2,b_out2,w_out3,b_out3,
                                               w_se1,w_se2,w_se3,w_se4, wsp);
  k_upsample_all<<<35328, 256, 0, stream>>>(wsp, out);
}